// Round 11
// baseline (241.093 us; speedup 1.0000x reference)
//
#include <hip/hip_runtime.h>
#include <hip/hip_bf16.h>

// Problem constants
#define NB   8      // batch
#define NM   288    // Bkk = 32*3*3
#define NN   1152   // Cww = 32*6*6
#define NUV  36     // w*w
#define ND   16

// ws layout (float offsets; P/Wt regions hold bf16 in half the space)
#define OFF_P    0
#define SZ_P     (NB*NUV*NM*ND)      // patches, bf16 [b][uv][m][k*4+j]
#define OFF_WT   (OFF_P + SZ_P)
#define SZ_WT    (32*NM*ND)          // W transposed, bf16 [z][m][i*4+j]
#define OFF_ACT  (OFF_WT + SZ_WT)
#define SZ_ACT   (NB*NUV*NM)         // log(act), f32 [b][uv][m]
#define OFF_L    (OFF_ACT + SZ_ACT)
#define SZ_L     (NB*NN*NM)          // ell, f32 [b][n][m] (contiguous)
#define OFF_LSE  (OFF_L + SZ_L)
#define SZ_LSE   (NB*NM)             // LSE over n, [b][m]
#define OFF_FLAG (OFF_LSE + SZ_LSE)  // dtype flag
#define OFF_PM   (OFF_FLAG + 16)
#define SZ_PM    (NB*NUV*NM)         // lse stage-1 partial max, [b][c][m]
#define OFF_PS   (OFF_PM + SZ_PM)
#define SZ_PS    (NB*NUV*NM)         // lse stage-1 partial sum, [b][c][m]

#define HALF_LOG_2PI 0.9189385332046727f
#define LOG_NN       7.049254841255839f   // log(1152)
#define NEG_BIG      (-1.0e30f)

__device__ __forceinline__ float ldin(const void* p, int i, int f32) {
    return f32 ? ((const float*)p)[i]
               : __bfloat162float(((const __hip_bfloat16*)p)[i]);
}

__device__ __forceinline__ unsigned short bfbits(float f) {
    __hip_bfloat16 h = __float2bfloat16(f);
    return __builtin_bit_cast(unsigned short, h);
}

// packed bf16x2 dot with f32 accumulate: d = a.lo*b.lo + a.hi*b.hi + c
__device__ __forceinline__ float dot2bf(unsigned a, unsigned b, float c) {
    float d;
    asm("v_dot2_f32_bf16 %0, %1, %2, %3" : "=v"(d) : "v"(a), "v"(b), "v"(c));
    return d;
}

// dtype sniff (r3-r10 verified: flag==0 on this harness; kept for safety)
__global__ void detect_kernel(const unsigned short* __restrict__ poses_u16,
                              int* __restrict__ flag) {
    if (blockIdx.x == 0 && threadIdx.x == 0) {
        int wild = 0;
        for (int i = 0; i < 64; ++i) {
            int ex = (poses_u16[i] >> 7) & 0xFF;
            if (ex >= 133) ++wild;
        }
        *flag = (wild >= 4) ? 1 : 0;
    }
}

// (b,s)-tiled prep: stage poses[b,:,s,:,:] + acts[b,s,:,:] in LDS, emit bf16 P
// (uint4 stores) and f32 log(act). Blocks 256..291 transpose W (uint4 stores).
__global__ __launch_bounds__(256) void prep_kernel(
    const void* __restrict__ poses, const void* __restrict__ acts,
    const void* __restrict__ Wb, __hip_bfloat16* __restrict__ P,
    __hip_bfloat16* __restrict__ Wt, float* __restrict__ A36,
    const int* __restrict__ flagp)
{
    const int f32 = *flagp;
    const int blk = blockIdx.x;
    const int tid = threadIdx.x;
    if (blk < 256) {
        __shared__ float ps[16 * 196];
        __shared__ float asld[196];
        const int b = blk >> 5, s = blk & 31;
        for (int e = tid; e < 16 * 196; e += 256) {
            int c = e / 196, hw = e % 196;
            ps[e] = ldin(poses, ((b * 16 + c) * 32 + s) * 196 + hw, f32);
        }
        for (int e = tid; e < 196; e += 256)
            asld[e] = ldin(acts, (b * 32 + s) * 196 + e, f32);
        __syncthreads();
        // P emit: 324 rows x 2 halves; one uint4 (8 bf16) per work item
        for (int o2 = tid; o2 < 648; o2 += 256) {
            int row = o2 >> 1, half = o2 & 1;
            int uv = row / 9, xy = row % 9;
            int u = uv / 6, vv2 = uv % 6;
            int x = xy / 3, y = xy % 3;
            unsigned pk[4];
#pragma unroll
            for (int h = 0; h < 4; ++h) {
                unsigned lohi[2];
#pragma unroll
                for (int e = 0; e < 2; ++e) {
                    int kj = half * 8 + h * 2 + e;
                    int k = kj >> 2, j = kj & 3;
                    int idx = u * 96 + vv2 * 16 + j * 4 + k;   // torch view scramble
                    int c = idx / 36, rem = idx % 36;
                    int wi = rem / 6, wj = rem % 6;
                    lohi[e] = bfbits(ps[c * 196 + (2 * wi + x) * 14 + (2 * wj + y)]);
                }
                pk[h] = lohi[0] | (lohi[1] << 16);
            }
            *((uint4*)(P + (((size_t)((b * 36 + uv) * 288 + s * 9 + xy)) << 4) + half * 8)) =
                make_uint4(pk[0], pk[1], pk[2], pk[3]);
        }
        for (int o = tid; o < 324; o += 256) {
            int uv = o / 9, xy = o % 9;
            int u = uv / 6, vv2 = uv % 6;
            int x = xy / 3, y = xy % 3;
            A36[(b * 36 + uv) * 288 + s * 9 + xy] =
                __logf(asld[(2 * u + x) * 14 + (2 * vv2 + y)]);
        }
    } else {
        int idx = (blk - 256) * 256 + tid;    // 0..9215 (z,m) pairs
        int z = idx / 288, m = idx % 288;
        unsigned pk[8];
#pragma unroll
        for (int h = 0; h < 8; ++h) {
            unsigned lo = bfbits(ldin(Wb, m * 512 + z * 16 + 2 * h, f32));
            unsigned hi = bfbits(ldin(Wb, m * 512 + z * 16 + 2 * h + 1, f32));
            pk[h] = lo | (hi << 16);
        }
        uint4* dst = (uint4*)(Wt + idx * 16);
        dst[0] = make_uint4(pk[0], pk[1], pk[2], pk[3]);
        dst[1] = make_uint4(pk[4], pk[5], pk[6], pk[7]);
    }
}

// ONE WAVE per (b,n): zero barriers, zero LDS. Lane owns m = lane + 64q
// (q=0..4; q=4 only lanes 0..31). m-reductions via 6-step shfl_xor butterfly;
// afterwards every lane holds mu/sigma^2 and finishes its own capsules' ell.
// OOB lane-q=4 loads land in adjacent ws regions (finite by construction) and
// are multiplied by w=0; ws is ~27.5 MB into a >=256 MB buffer.
__global__ __launch_bounds__(256) void em_iter(
    const unsigned short* __restrict__ wsP, const unsigned short* __restrict__ wsWt,
    const float* __restrict__ wsA, float* __restrict__ wsL,
    const float* __restrict__ wsLSE,
    const void* __restrict__ beta_v,
    const void* __restrict__ beta_a,
    const void* __restrict__ lambda_,
    void* __restrict__ outv, const int* __restrict__ flagp, int iter)
{
    const int tid  = threadIdx.x;
    const int lane = tid & 63;
    const int bn   = blockIdx.x * 4 + (tid >> 6);   // wave id == b*NN+n
    const int b    = bn / NN;
    const int n    = bn % NN;
    const int z    = n / NUV;
    const int uv   = n % NUV;
    const int g    = b * NUV + uv;

    // ---- issue all W/P row loads up front (packed bf16, 32 B per row) ----
    uint4 WQ0[5], WQ1[5], PQ0[5], PQ1[5];
#pragma unroll
    for (int q = 0; q < 5; ++q) {
        const int m = lane + (q << 6);
        const uint4* Wq = (const uint4*)(wsWt + ((z * NM + m) << 4));
        const uint4* Pq = (const uint4*)(wsP + ((g * NM + m) << 4));
        WQ0[q] = Wq[0]; WQ1[q] = Wq[1];
        PQ0[q] = Pq[0]; PQ1[q] = Pq[1];
    }

    // ---- routing weights: t per capsule, wave max, w = exp(t - M) ----
    const float* Arow = wsA + g * NM;
    const float* Lrow = wsL + (size_t)bn * NM;
    const float* Srow = wsLSE + b * NM;
    float t[5], lact[5];
#pragma unroll
    for (int q = 0; q < 5; ++q) {
        const int m = lane + (q << 6);
        const bool on = (q < 4) || (lane < 32);
        const float la = on ? Arow[m] : 0.f;
        lact[q] = la;
        float tv;
        if (iter == 0) tv = la - LOG_NN;
        else tv = (on ? (Lrow[m] - Srow[m]) : 0.f) + la;
        t[q] = on ? fmaxf(tv, NEG_BIG) : NEG_BIG;
    }
    float M = t[0];
#pragma unroll
    for (int q = 1; q < 5; ++q) M = fmaxf(M, t[q]);
#pragma unroll
    for (int off = 1; off < 64; off <<= 1) M = fmaxf(M, __shfl_xor(M, off));
    float w[5];
#pragma unroll
    for (int q = 0; q < 5; ++q) w[q] = __expf(t[q] - M);   // inactive: exp(-1e30)=0

    // ---- votes + weighted accumulation (all in registers) ----
    float v[5][16];
    float S1[16], S2[16];
#pragma unroll
    for (int d = 0; d < 16; ++d) { S1[d] = 0.f; S2[d] = 0.f; }
    float sW = 0.f;
#pragma unroll
    for (int q = 0; q < 5; ++q) {
        const unsigned Wa[4]  = {WQ0[q].x, WQ0[q].z, WQ1[q].x, WQ1[q].z};
        const unsigned Wb_[4] = {WQ0[q].y, WQ0[q].w, WQ1[q].y, WQ1[q].w};
        const unsigned Pa[4]  = {PQ0[q].x, PQ0[q].z, PQ1[q].x, PQ1[q].z};
        const unsigned Pb[4]  = {PQ0[q].y, PQ0[q].w, PQ1[q].y, PQ1[q].w};
        const float wq = w[q];
        sW += wq;
#pragma unroll
        for (int i = 0; i < 4; ++i)
#pragma unroll
            for (int k = 0; k < 4; ++k) {
                const int d = i * 4 + k;
                float vv = dot2bf(Wa[i], Pa[k], dot2bf(Wb_[i], Pb[k], 0.f));
                v[q][d] = vv;
                float p = wq * vv;
                S1[d] += p;
                S2[d] = fmaf(p, vv, S2[d]);
            }
    }

    // ---- wave all-reduce butterfly: sW, S1[16], S2[16] (no barrier) ----
#pragma unroll
    for (int off = 1; off < 64; off <<= 1) {
        sW += __shfl_xor(sW, off);
#pragma unroll
        for (int d = 0; d < 16; ++d) {
            S1[d] += __shfl_xor(S1[d], off);
            S2[d] += __shfl_xor(S2[d], off);
        }
    }

    // ---- stats (every lane redundantly; no broadcast needed) ----
    const float rs = 1.f / sW;
    float mu[16], nhi[16], ltc[16];
    float lss = 0.f;
#pragma unroll
    for (int d = 0; d < 16; ++d) {
        float m1 = S1[d] * rs;
        float ss = fmaxf(S2[d] * rs - m1 * m1, 1e-30f);   // E[v^2]-mu^2 (r4-r10)
        float lg = __logf(ss);
        mu[d]  = m1;
        nhi[d] = -0.5f / ss;
        ltc[d] = fmaf(-0.5f, lg, -HALF_LOG_2PI);
        lss += lg;
    }

    if (iter < 3) {
        // ell[m] = log(act) + LSE_d(log_p), serial per owned capsule
#pragma unroll
        for (int q = 0; q < 5; ++q) {
            float lp[16];
            float Mq = NEG_BIG;
#pragma unroll
            for (int d = 0; d < 16; ++d) {
                float df = v[q][d] - mu[d];
                lp[d] = fmaf(df * df, nhi[d], ltc[d]);
                Mq = fmaxf(Mq, lp[d]);
            }
            float s = 0.f;
#pragma unroll
            for (int d = 0; d < 16; ++d) s += __expf(lp[d] - Mq);
            if ((q < 4) || (lane < 32))
                wsL[(size_t)bn * NM + lane + (q << 6)] = lact[q] + Mq + __logf(s);
        }
    } else {
        const int f32 = *flagp;
        if (lane == 0) {
            if (f32) {
                float* o = (float*)outv + ((size_t)bn << 4);
#pragma unroll
                for (int d = 0; d < 16; ++d) o[d] = mu[d];
            } else {
                unsigned pk[8];
#pragma unroll
                for (int h = 0; h < 8; ++h)
                    pk[h] = (unsigned)bfbits(mu[2 * h]) |
                            ((unsigned)bfbits(mu[2 * h + 1]) << 16);
                uint4* o = (uint4*)((__hip_bfloat16*)outv + ((size_t)bn << 4));
                o[0] = make_uint4(pk[0], pk[1], pk[2], pk[3]);
                o[1] = make_uint4(pk[4], pk[5], pk[6], pk[7]);
            }
            float sumR = __expf(M) * sW;   // true sum_R (M <= 0)
            float bv  = ldin(beta_v, n, f32);
            float c   = (16.f * bv + lss) * sumR;   // sum_d (bv + log ss)
            float lam = ldin(lambda_, 0, f32);
            float ba  = ldin(beta_a, n, f32);
            float ao  = 1.f / (1.f + __expf(-(lam * (ba - c))));
            int oi = NB * NN * ND + bn;
            if (f32) ((float*)outv)[oi] = ao;
            else ((__hip_bfloat16*)outv)[oi] = __float2bfloat16(ao);
        }
    }
}

// LSE stage 1: block (b,c) covers 32 rows n = 32c..32c+31 of contiguous
// L[b][n][m]; thread m walks the column (coalesced). Two passes (L2-hot).
__global__ __launch_bounds__(288) void lse1_kernel(const float* __restrict__ L,
                                                   float* __restrict__ PM,
                                                   float* __restrict__ PS)
{
    const int tid = threadIdx.x;
    const int blk = blockIdx.x;           // b*36 + c
    const int b = blk / NUV;
    const int c = blk % NUV;
    const float* base = L + ((size_t)b * NN + c * 32) * NM + tid;
    float mx = NEG_BIG;
#pragma unroll
    for (int r = 0; r < 32; ++r) mx = fmaxf(mx, base[r * NM]);
    float s = 0.f;
#pragma unroll
    for (int r = 0; r < 32; ++r) s += __expf(base[r * NM] - mx);
    PM[blk * NM + tid] = mx;
    PS[blk * NM + tid] = s;
}

// LSE stage 2: combine 36 chunk partials per (b,m) row. 2304 rows.
__global__ void lse2_kernel(const float* __restrict__ PM,
                            const float* __restrict__ PS,
                            float* __restrict__ LSE)
{
    int t = blockIdx.x * 256 + threadIdx.x;   // b*288 + m
    if (t >= NB * NM) return;
    int b = t / NM, m = t % NM;
    const float* pm = PM + (size_t)b * NUV * NM + m;
    const float* ps = PS + (size_t)b * NUV * NM + m;
    float mx = NEG_BIG;
#pragma unroll
    for (int cc = 0; cc < NUV; ++cc) mx = fmaxf(mx, pm[cc * NM]);
    float s = 0.f;
#pragma unroll
    for (int cc = 0; cc < NUV; ++cc) s += ps[cc * NM] * __expf(pm[cc * NM] - mx);
    LSE[t] = mx + __logf(s);
}

extern "C" void kernel_launch(void* const* d_in, const int* in_sizes, int n_in,
                              void* d_out, int out_size, void* d_ws, size_t ws_size,
                              hipStream_t stream)
{
    const void* poses = d_in[0];
    const void* acts  = d_in[1];
    const void* lam   = d_in[2];
    const void* Wb    = d_in[3];
    const void* bv    = d_in[4];
    const void* ba    = d_in[5];

    float* ws  = (float*)d_ws;
    __hip_bfloat16* P  = (__hip_bfloat16*)(ws + OFF_P);
    __hip_bfloat16* Wt = (__hip_bfloat16*)(ws + OFF_WT);
    float* A36 = ws + OFF_ACT;
    float* L   = ws + OFF_L;
    float* LSE = ws + OFF_LSE;
    int*  flag = (int*)(ws + OFF_FLAG);
    float* PM  = ws + OFF_PM;
    float* PS  = ws + OFF_PS;

    detect_kernel<<<1, 64, 0, stream>>>((const unsigned short*)poses, flag);

    prep_kernel<<<292, 256, 0, stream>>>(poses, acts, Wb, P, Wt, A36, flag);

    for (int it = 0; it < 4; ++it) {
        em_iter<<<NB * NN / 4, 256, 0, stream>>>((const unsigned short*)P,
                                                 (const unsigned short*)Wt,
                                                 A36, L, LSE, bv, ba, lam,
                                                 d_out, flag, it);
        if (it < 3) {
            lse1_kernel<<<NB * NUV, 288, 0, stream>>>(L, PM, PS);
            lse2_kernel<<<9, 256, 0, stream>>>(PM, PS, LSE);
        }
    }
}